// Round 10
// baseline (790.038 us; speedup 1.0000x reference)
//
#include <hip/hip_runtime.h>

typedef unsigned short u16;
typedef unsigned int u32;
typedef __bf16 bf16x8 __attribute__((ext_vector_type(8)));
typedef float f32x4 __attribute__((ext_vector_type(4)));

#define MFMA16(a, b, c) __builtin_amdgcn_mfma_f32_16x16x32_bf16((a), (b), (c), 0, 0, 0)

// ---- constants ----
#define S_LEN 2048
#define D_HEAD 128
#define NHEADS 16
#define NBH 32          // B*HEADS
#define QDIM 2048
#define NPROJ 22528     // 3*INNER + 2*MLP_HID
#define NQKV 6144       // 3*INNER
#define NMLP 16384      // 2*MLP_HID
#define NCAT 10240      // INNER + MLP_HID
#define MROWS 4096      // B*S

#define BARRIER() __builtin_amdgcn_s_barrier()
#define FENCE() asm volatile("" ::: "memory")
#define WAITVM0() asm volatile("s_waitcnt vmcnt(0)" ::: "memory")
#define WAITVM4() asm volatile("s_waitcnt vmcnt(4)" ::: "memory")

__device__ __forceinline__ float bf2f(u16 u) { return __uint_as_float(((u32)u) << 16); }
__device__ __forceinline__ u16 f2bf(float f) {
  u32 u = __float_as_uint(f);
  return (u16)((u + 0x7FFFu + ((u >> 16) & 1u)) >> 16);
}
__device__ __forceinline__ void gld16(const void* g, void* l) {
  __builtin_amdgcn_global_load_lds((__attribute__((address_space(1))) void*)(g),
                                   (__attribute__((address_space(3))) void*)(l), 16, 0, 0);
}

// ---------------- f32 -> bf16 elementwise (vectorized) ----------------
__global__ __launch_bounds__(256) void f32_to_bf16(const float* __restrict__ in,
                                                   u16* __restrict__ out) {
  const u32 i = blockIdx.x * 256 + threadIdx.x;  // one float4 per thread
  const float4 v = ((const float4*)in)[i];
  uint2 o;
  o.x = (u32)f2bf(v.x) | ((u32)f2bf(v.y) << 16);
  o.y = (u32)f2bf(v.z) | ((u32)f2bf(v.w) << 16);
  ((uint2*)out)[i] = o;
}

// -------- transpose-convert v3: in[R][C] f32 -> out[C][R] bf16, wide stores --------
template <int REMAP>
__global__ __launch_bounds__(256) void transpose_f32_bf16(const float* __restrict__ in,
                                                          u16* __restrict__ out, int R, int C) {
  __shared__ u16 tile[64][260];
  const int t = threadIdx.x;
  const int tx = t & 63;   // column (C-dim)
  const int ty = t >> 6;   // 0..3
  const int c0 = blockIdx.x * 64;
  const int r0 = blockIdx.y * 256;

#pragma unroll 8
  for (int it = 0; it < 64; ++it) {
    const int rr = it * 4 + ty;
    tile[tx][rr] = f2bf(in[(size_t)(r0 + rr) * C + c0 + tx]);
  }
  __syncthreads();

  const int pos = t & 63;
#pragma unroll 4
  for (int i = 0; i < 16; ++i) {
    const int cc = i * 4 + (t >> 6);
    int orow = c0 + cc;
    if (REMAP && orow >= NQKV) {
      const int c = orow - NQKV;
      const int f = c & 8191;
      const int sel = c >> 13;
      orow = NQKV + (((f >> 4) << 5) | (sel << 4) | (f & 15));
    }
    const u32 lo = (u32)tile[cc][pos * 4] | ((u32)tile[cc][pos * 4 + 1] << 16);
    const u32 hi = (u32)tile[cc][pos * 4 + 2] | ((u32)tile[cc][pos * 4 + 3] << 16);
    uint2 v;
    v.x = lo;
    v.y = hi;
    *(uint2*)&out[(size_t)orow * R + r0 + pos * 4] = v;
  }
}

// ============ 256x256 ring-4 pipelined bf16 GEMM + fused SwiGLU (MLP) ============
// 512 thr = 8 waves (2M x 4N), per-wave 128x64 out, BK=32, LDS ring-4 per operand
// (4 x 16KB each, 128KB total). Stage tile kt+3 into slot (kt+3)&3 — ring distance
// >= 2 from any reader => no WAR hazard anywhere. Counted vmcnt(4) once per tile
// (kt+3's 4 loads stay in flight); vmcnt(0) only for the last 4 tiles. Per phase:
// {next-phase ds_reads ; 2 gld16 ; barrier ; setprio+16 MFMA ; barrier}. Compiler
// inserts counted lgkmcnt for ds_read->MFMA deps (no sched_barrier pinning).
// Tile layout: 128B pseudo-rows (2 rows of 32 bf16), granule XOR over 8 -> frag
// reads are 2-way (free) bank-wise; gld16 source pre-swizzled to match (rule #21).

__device__ __forceinline__ void stage32(const u16* __restrict__ src, int K, int base,
                                        u16* dst, int k0, int t) {
#pragma unroll
  for (int jj = 0; jj < 2; ++jj) {
    const int o = (jj * 512 + t) * 16;   // byte offset in 16KB tile
    const int pr = o >> 7;               // 128B pseudo-row
    const int gs = (o & 127) >> 4;       // stored granule 0..7
    const int ga = gs ^ (pr & 7);        // logical granule
    const int row = pr * 2 + (ga >> 2);  // actual tile row (0..255)
    const int k8 = ga & 3;               // k-granule (8 bf16 each)
    gld16(src + (size_t)(base + row) * K + k0 + k8 * 8,
          dst + (jj * 512 + (t & ~63)) * 8);
  }
}

__device__ __forceinline__ bf16x8 rd32(const u16* buf, int row, int lg) {
  const int pr = row >> 1;
  const int ga = ((row & 1) << 2) | lg;
  const int gs = ga ^ (pr & 7);
  return *(const bf16x8*)&buf[pr * 64 + gs * 8];
}

#define ITER(KT, BCUR, BNXT)                                                        \
  {                                                                                 \
    const int d_ = (KT) & 3, dn_ = ((KT) + 1) & 3, ds_ = ((KT) + 3) & 3;            \
    /* P0: read aB (ih=1); stage A(kt+3); MFMA ih=0 */                              \
    _Pragma("unroll") for (int i = 0; i < 4; ++i)                                   \
        aB[i] = rd32(&As[d_][0], wm + 64 + i * 16 + lr, lg);                        \
    if ((KT) + 3 < NT) stage32(A, K, m0, &As[ds_][0], ((KT) + 3) * 32, t);          \
    BARRIER();                                                                      \
    FENCE();                                                                        \
    __builtin_amdgcn_s_setprio(1);                                                  \
    _Pragma("unroll") for (int i = 0; i < 4; ++i)                                   \
    _Pragma("unroll") for (int j = 0; j < 4; ++j)                                   \
        acc[i][j] = MFMA16(aA[i], BCUR[j], acc[i][j]);                              \
    __builtin_amdgcn_s_setprio(0);                                                  \
    BARRIER();                                                                      \
    FENCE();                                                                        \
    /* P1: read next tile's aA + B; stage B(kt+3); MFMA ih=1 */                     \
    if ((KT) + 1 < NT) {                                                            \
      _Pragma("unroll") for (int i = 0; i < 4; ++i)                                 \
          aA[i] = rd32(&As[dn_][0], wm + i * 16 + lr, lg);                          \
      _Pragma("unroll") for (int j = 0; j < 4; ++j)                                 \
          BNXT[j] = rd32(&Bs[dn_][0], wn + j * 16 + lr, lg);                        \
    }                                                                               \
    if ((KT) + 3 < NT) stage32(Bt, K, n0, &Bs[ds_][0], ((KT) + 3) * 32, t);         \
    BARRIER();                                                                      \
    FENCE();                                                                        \
    __builtin_amdgcn_s_setprio(1);                                                  \
    _Pragma("unroll") for (int i = 0; i < 4; ++i)                                   \
    _Pragma("unroll") for (int j = 0; j < 4; ++j)                                   \
        acc[4 + i][j] = MFMA16(aB[i], BCUR[j], acc[4 + i][j]);                      \
    __builtin_amdgcn_s_setprio(0);                                                  \
    if ((KT) >= NT - 4) {                                                           \
      WAITVM0();                                                                    \
    } else {                                                                        \
      WAITVM4();                                                                    \
    }                                                                               \
    BARRIER();                                                                      \
    FENCE();                                                                        \
  }

__global__ __launch_bounds__(512, 1) void gemm_mlp(const u16* __restrict__ A,
                                                   const u16* __restrict__ Bt,
                                                   u16* __restrict__ Cat, int K) {
  __shared__ u16 As[4][256 * 32];
  __shared__ u16 Bs[4][256 * 32];
  const int t = threadIdx.x;
  const int l = t & 63;
  const int w = t >> 6;
  const int lr = l & 15;
  const int lg = l >> 4;
  const int m0 = blockIdx.y * 256;
  const int n0 = blockIdx.x * 256;
  const int wm = (w >> 2) * 128;
  const int wn = (w & 3) * 64;
  const int NT = K >> 5;  // 64

  f32x4 acc[8][4] = {};
  bf16x8 aA[4], aB[4], bC[4], bD[4];

  // prologue: stage tiles 0,1,2 (12 loads); drain tiles 0,1; preload tile0 frags
  stage32(A, K, m0, &As[0][0], 0, t);
  stage32(Bt, K, n0, &Bs[0][0], 0, t);
  stage32(A, K, m0, &As[1][0], 32, t);
  stage32(Bt, K, n0, &Bs[1][0], 32, t);
  stage32(A, K, m0, &As[2][0], 64, t);
  stage32(Bt, K, n0, &Bs[2][0], 64, t);
  WAITVM4();
  BARRIER();
  FENCE();
#pragma unroll
  for (int i = 0; i < 4; ++i) aA[i] = rd32(&As[0][0], wm + i * 16 + lr, lg);
#pragma unroll
  for (int j = 0; j < 4; ++j) bC[j] = rd32(&Bs[0][0], wn + j * 16 + lr, lg);

  for (int kt = 0; kt < NT; kt += 2) {
    ITER(kt, bC, bD)
    ITER(kt + 1, bD, bC)
  }

  // epilogue: fused SwiGLU (B rows interleaved m1/m2 in 16-row groups)
#pragma unroll
  for (int i = 0; i < 8; ++i)
#pragma unroll
    for (int jj = 0; jj < 2; ++jj)
#pragma unroll
      for (int r = 0; r < 4; ++r) {
        const int row = m0 + wm + i * 16 + lg * 4 + r;
        const float a1 = acc[i][2 * jj][r];
        const float a2 = acc[i][2 * jj + 1][r];
        const float fz = a1 / (1.f + __expf(-a1)) * a2;
        const int col = ((n0 + wn) >> 1) + jj * 16 + lr;
        Cat[(size_t)row * NCAT + col] = f2bf(fz);
      }
}

// ---------------- 128x128 bf16 GEMM (m97 structure) — GEMM2 (f32 + bias) ----------------
__global__ __launch_bounds__(256, 2) void gemm_bt(const u16* __restrict__ A,
                                                  const u16* __restrict__ Bt,
                                                  float* __restrict__ C,
                                                  const float* __restrict__ bias, int N, int K) {
  __shared__ u16 As[128 * 64];
  __shared__ u16 Bs[128 * 64];
  const int t = threadIdx.x;
  const int l = t & 63;
  const int w = t >> 6;
  const int lr = l & 15;
  const int lg = l >> 4;
  const int m0 = blockIdx.y * 128;
  const int n0 = blockIdx.x * 128;
  const int wm = (w >> 1) * 64;
  const int wn = (w & 1) * 64;

  f32x4 acc[4][4] = {};
  const int obase = w * 1024 + l * 16;

  for (int k0 = 0; k0 < K; k0 += 64) {
#pragma unroll
    for (int rnd = 0; rnd < 4; ++rnd) {
      const int o = obase + rnd * 4096;
      const int row = o >> 7;
      const int g = (o & 127) >> 4;
      const int gs = g ^ (row & 7);
      gld16(A + (size_t)(m0 + row) * K + k0 + gs * 8, &As[rnd * 2048 + w * 512]);
      gld16(Bt + (size_t)(n0 + row) * K + k0 + gs * 8, &Bs[rnd * 2048 + w * 512]);
    }
    __syncthreads();

    bf16x8 af[4][2], bfr[4][2];
#pragma unroll
    for (int i = 0; i < 4; ++i) {
#pragma unroll
      for (int kc = 0; kc < 2; ++kc) {
        const int ra = wm + i * 16 + lr;
        af[i][kc] = *(const bf16x8*)&As[ra * 64 + (((kc * 4 + lg) ^ (ra & 7)) * 8)];
        const int rb = wn + i * 16 + lr;
        bfr[i][kc] = *(const bf16x8*)&Bs[rb * 64 + (((kc * 4 + lg) ^ (rb & 7)) * 8)];
      }
    }
#pragma unroll
    for (int kc = 0; kc < 2; ++kc)
#pragma unroll
      for (int i = 0; i < 4; ++i)
#pragma unroll
        for (int j = 0; j < 4; ++j)
          acc[i][j] = MFMA16(af[i][kc], bfr[j][kc], acc[i][j]);
    __syncthreads();
  }

#pragma unroll
  for (int i = 0; i < 4; ++i)
#pragma unroll
    for (int j = 0; j < 4; ++j)
#pragma unroll
      for (int r = 0; r < 4; ++r) {
        const int row = m0 + wm + i * 16 + lg * 4 + r;
        const int col = n0 + wn + j * 16 + lr;
        C[(size_t)row * N + col] = acc[i][j][r] + bias[col];
      }
}

// ------------- QKV GEMM with fused RMSNorm + RoPE + V-transpose epilogue -------------
__global__ __launch_bounds__(256, 2) void gemm_qkv(const u16* __restrict__ A,
                                                   const u16* __restrict__ Bt,
                                                   const float* __restrict__ cosT,
                                                   const float* __restrict__ sinT,
                                                   const float* __restrict__ wq,
                                                   const float* __restrict__ wk,
                                                   u16* __restrict__ Qb, u16* __restrict__ Kb,
                                                   u16* __restrict__ Vt, int K) {
  __shared__ u16 smem[2][128 * 64];  // As | Bs ; reused as 128x128 V-tile
  __shared__ float redbuf[2][128];
  u16* As = smem[0];
  u16* Bs = smem[1];
  const int t = threadIdx.x;
  const int l = t & 63;
  const int w = t >> 6;
  const int lr = l & 15;
  const int lg = l >> 4;
  const int m0 = blockIdx.y * 128;
  const int n0 = blockIdx.x * 128;
  const int wm = (w >> 1) * 64;
  const int wn = (w & 1) * 64;

  f32x4 acc[4][4] = {};
  const int obase = w * 1024 + l * 16;

  for (int k0 = 0; k0 < K; k0 += 64) {
#pragma unroll
    for (int rnd = 0; rnd < 4; ++rnd) {
      const int o = obase + rnd * 4096;
      const int row = o >> 7;
      const int g = (o & 127) >> 4;
      const int gs = g ^ (row & 7);
      gld16(A + (size_t)(m0 + row) * K + k0 + gs * 8, As + rnd * 2048 + w * 512);
      gld16(Bt + (size_t)(n0 + row) * K + k0 + gs * 8, Bs + rnd * 2048 + w * 512);
    }
    __syncthreads();

    bf16x8 af[4][2], bfr[4][2];
#pragma unroll
    for (int i = 0; i < 4; ++i) {
#pragma unroll
      for (int kc = 0; kc < 2; ++kc) {
        const int ra = wm + i * 16 + lr;
        af[i][kc] = *(const bf16x8*)&As[ra * 64 + (((kc * 4 + lg) ^ (ra & 7)) * 8)];
        const int rb = wn + i * 16 + lr;
        bfr[i][kc] = *(const bf16x8*)&Bs[rb * 64 + (((kc * 4 + lg) ^ (rb & 7)) * 8)];
      }
    }
#pragma unroll
    for (int kc = 0; kc < 2; ++kc)
#pragma unroll
      for (int i = 0; i < 4; ++i)
#pragma unroll
        for (int j = 0; j < 4; ++j)
          acc[i][j] = MFMA16(af[i][kc], bfr[j][kc], acc[i][j]);
    __syncthreads();
  }

  const int type = n0 >> 11;  // 0=Q, 1=K, 2=V
  const int h = (n0 >> 7) & 15;
  const int b = m0 >> 11;
  const int s0 = m0 & 2047;
  const int bh = b * 16 + h;

  if (type == 2) {
    u16* vt = smem[0];  // 128x128 u16 = 32 KB
#pragma unroll
    for (int i = 0; i < 4; ++i)
#pragma unroll
      for (int j = 0; j < 4; ++j)
#pragma unroll
        for (int r = 0; r < 4; ++r) {
          const int s_loc = wm + i * 16 + lg * 4 + r;
          const int d = wn + j * 16 + lr;
          vt[d * 128 + (s_loc ^ ((d & 7) << 3))] = f2bf(acc[i][j][r]);
        }
    __syncthreads();
    const int g = t & 15;
#pragma unroll
    for (int i = 0; i < 8; ++i) {
      const int d2 = i * 16 + (t >> 4);
      const bf16x8 v = *(const bf16x8*)&vt[d2 * 128 + ((g ^ (d2 & 7)) * 8)];
      *(bf16x8*)&Vt[((size_t)(bh * 128 + d2)) * S_LEN + s0 + g * 8] = v;
    }
    return;
  }

  u16* dst = (type == 0) ? Qb : Kb;

  float ssum[4][4];
#pragma unroll
  for (int i = 0; i < 4; ++i)
#pragma unroll
    for (int r = 0; r < 4; ++r) {
      float p = acc[i][0][r] * acc[i][0][r] + acc[i][1][r] * acc[i][1][r] +
                acc[i][2][r] * acc[i][2][r] + acc[i][3][r] * acc[i][3][r];
      p += __shfl_xor(p, 1);
      p += __shfl_xor(p, 2);
      p += __shfl_xor(p, 4);
      p += __shfl_xor(p, 8);
      ssum[i][r] = p;
    }
  if (lr == 0) {
#pragma unroll
    for (int i = 0; i < 4; ++i)
#pragma unroll
      for (int r = 0; r < 4; ++r) redbuf[wn >> 6][wm + i * 16 + lg * 4 + r] = ssum[i][r];
  }
  __syncthreads();

  const float* wgt = type ? wk : wq;
  // Q pre-scale: 128^-0.5 * log2(e) (attention uses exp2)
  const float sc = type ? 1.0f : 0.12751744f;
#pragma unroll
  for (int i = 0; i < 4; ++i)
#pragma unroll
    for (int r = 0; r < 4; ++r) {
      const int lrow = wm + i * 16 + lg * 4 + r;
      const float tot = redbuf[0][lrow] + redbuf[1][lrow];
      const float rsq = rsqrtf(tot * (1.0f / 128.0f) + 1e-5f) * sc;
      const int s = (m0 + lrow) & 2047;
      const size_t rbase = ((size_t)bh * S_LEN + s) * 128;
#pragma unroll
      for (int j = 0; j < 4; ++j) {
        const int col = wn + j * 16 + lr;
        const float xn = acc[i][j][r] * rsq * wgt[col];
        const float pr = __shfl_xor(xn, 1);
        const float c = cosT[s * 128 + col];
        const float sn = sinT[s * 128 + col];
        const float val = (col & 1) ? (xn * c + pr * sn) : (xn * c - pr * sn);
        dst[rbase + col] = f2bf(val);
      }
    }
}

// ---------------- flash attention: 4 waves x 32 q-rows, KV tile = 64 ----------------
__global__ __launch_bounds__(256, 2) void attn_fwd(const u16* __restrict__ Qb,
                                                   const u16* __restrict__ Kb,
                                                   const u16* __restrict__ Vt,
                                                   u16* __restrict__ Cat) {
  __shared__ u16 Ks[2][64 * 128];   // [key][d], swz g^=key&7
  __shared__ u16 Vs[2][128 * 64];   // [d][key], swz g^=d&7
  __shared__ u16 Ps[4][32 * 64];    // per-wave P [q][key], swz g^=q&7

  const int t = threadIdx.x;
  const int l = t & 63;
  const int w = t >> 6;
  const int lr = l & 15;
  const int lg = l >> 4;
  const int swz = (blockIdx.x & 7) * 64 + (blockIdx.x >> 3);
  const int qt = swz & 15;
  const int bh = swz >> 4;
  const int b = bh >> 4;
  const int h = bh & 15;
  const int q0 = qt * 128 + w * 32;
  const int obase = w * 1024 + l * 16;

  const size_t kbase = (size_t)bh * S_LEN * 128;
  const size_t vbase = (size_t)bh * 128 * S_LEN;

  bf16x8 qf[2][4];
#pragma unroll
  for (int im = 0; im < 2; ++im)
#pragma unroll
    for (int kc = 0; kc < 4; ++kc)
      qf[im][kc] =
          *(const bf16x8*)&Qb[((size_t)bh * S_LEN + q0 + im * 16 + lr) * 128 + kc * 32 + lg * 8];

  f32x4 oacc[2][8] = {};
  float lrun[2][4] = {};

  u16* P = Ps[w];

  auto stageKV = [&](int buf, int kt2) {
    const int kk0 = kt2 * 64;
#pragma unroll
    for (int rnd = 0; rnd < 4; ++rnd) {
      const int o = obase + rnd * 4096;
      {
        const int key = o >> 8;
        const int g = (o & 255) >> 4;
        const int gs = g ^ (key & 7);
        gld16(Kb + kbase + (size_t)(kk0 + key) * 128 + gs * 8,
              &Ks[buf][rnd * 2048 + w * 512]);
      }
      {
        const int d = o >> 7;
        const int g = (o & 127) >> 4;
        const int gs = g ^ (d & 7);
        gld16(Vt + vbase + (size_t)d * S_LEN + kk0 + gs * 8,
              &Vs[buf][rnd * 2048 + w * 512]);
      }
    }
  };

  stageKV(0, 0);
  WAITVM0();
  BARRIER();

  int cur = 0;
  for (int kt = 0; kt < 32; ++kt) {
    if (kt + 1 < 32) stageKV(cur ^ 1, kt + 1);

    const u16* Kc = &Ks[cur][0];
    const u16* Vc = &Vs[cur][0];

    f32x4 sf[2][4] = {};
    __builtin_amdgcn_s_setprio(1);
#pragma unroll
    for (int j = 0; j < 4; ++j) {
      const int kr = j * 16 + lr;
      bf16x8 kf[4];
#pragma unroll
      for (int kc = 0; kc < 4; ++kc)
        kf[kc] = *(const bf16x8*)&Kc[kr * 128 + (((kc * 4 + lg) ^ (kr & 7)) * 8)];
#pragma unroll
      for (int kc = 0; kc < 4; ++kc)
#pragma unroll
        for (int im = 0; im < 2; ++im)
          sf[im][j] = MFMA16(qf[im][kc], kf[kc], sf[im][j]);
    }
    __builtin_amdgcn_s_setprio(0);

#pragma unroll
    for (int im = 0; im < 2; ++im)
#pragma unroll
      for (int r = 0; r < 4; ++r) {
        float psum = 0.f;
#pragma unroll
        for (int j = 0; j < 4; ++j) {
          const float pv = exp2f(sf[im][j][r]);
          sf[im][j][r] = pv;
          psum += pv;
        }
        lrun[im][r] += psum;
      }

#pragma unroll
    for (int im = 0; im < 2; ++im)
#pragma unroll
      for (int j = 0; j < 4; ++j)
#pragma unroll
        for (int r = 0; r < 4; ++r) {
          const int q = im * 16 + lg * 4 + r;
          const int key = j * 16 + lr;
          const int g = key >> 3;
          P[q * 64 + ((g ^ (q & 7)) * 8) + (key & 7)] = f2bf(sf[im][j][r]);
        }

    __builtin_amdgcn_s_setprio(1);
#pragma unroll
    for (int kc = 0; kc < 2; ++kc) {
      bf16x8 pa[2];
#pragma unroll
      for (int im = 0; im < 2; ++im) {
        const int q = im * 16 + lr;
        pa[im] = *(const bf16x8*)&P[q * 64 + (((kc * 4 + lg) ^ (q & 7)) * 8)];
      }
#pragma unroll
      for (int df = 0; df < 8; ++df) {
        const int d = df * 16 + lr;
        const bf16x8 vb = *(const bf16x8*)&Vc[d * 64 + (((kc * 4 + lg) ^ (d & 7)) * 8)];
#pragma unroll
        for (int im = 0; im < 2; ++im) oacc[im][df] = MFMA16(pa[im], vb, oacc[im][df]);
      }
    }
    __builtin_amdgcn_s_setprio(0);

    WAITVM0();
    BARRIER();
    cur ^= 1;
  }

#pragma unroll
  for (int im = 0; im < 2; ++im)
#pragma unroll
    for (int r = 0; r < 4; ++r) {
      float tot = lrun[im][r];
      tot += __shfl_xor(tot, 1);
      tot += __shfl_xor(tot, 2);
      tot += __shfl_xor(tot, 4);
      tot += __shfl_xor(tot, 8);
      const float inv = 1.0f / tot;
      const int row = b * S_LEN + q0 + im * 16 + lg * 4 + r;
#pragma unroll
      for (int df = 0; df < 8; ++df) {
        const int col = h * 128 + df * 16 + lr;
        Cat[(size_t)row * NCAT + col] = f2bf(oacc[im][df][r] * inv);
      }
    }
}

// ---------------- launch ----------------
extern "C" void kernel_launch(void* const* d_in, const int* in_sizes, int n_in, void* d_out,
                              int out_size, void* d_ws, size_t ws_size, hipStream_t stream) {
  (void)in_sizes; (void)n_in; (void)out_size; (void)ws_size;
  const float* hs = (const float*)d_in[0];
  const float* rcos = (const float*)d_in[1];
  const float* rsin = (const float*)d_in[2];
  const float* Wqkv = (const float*)d_in[3];
  const float* wq = (const float*)d_in[4];
  const float* wk = (const float*)d_in[5];
  const float* Wout = (const float*)d_in[6];
  const float* bout = (const float*)d_in[7];
  float* out = (float*)d_out;

  char* ws = (char*)d_ws;
  size_t off = 0;
  auto nxt = [&](size_t bytes) {
    char* p = ws + off;
    off += (bytes + 255) & ~(size_t)255;
    return p;
  };
  u16* Xb = (u16*)nxt((size_t)MROWS * QDIM * 2);          // 16.8 MB
  u16* Wqkvt = (u16*)nxt((size_t)NPROJ * QDIM * 2);       // 92.3 MB
  u16* Woutt = (u16*)nxt((size_t)QDIM * NCAT * 2);        // 41.9 MB
  u16* Qb = (u16*)nxt((size_t)NBH * S_LEN * D_HEAD * 2);  // 16.8 MB
  u16* Kb = (u16*)nxt((size_t)NBH * S_LEN * D_HEAD * 2);
  u16* Vt = (u16*)nxt((size_t)NBH * S_LEN * D_HEAD * 2);
  u16* Cat = (u16*)nxt((size_t)MROWS * NCAT * 2);         // 83.9 MB

  // 1) convert / transpose to bf16 (Wqkv with MLP m1/m2 interleave remap)
  f32_to_bf16<<<(MROWS * QDIM / 4) / 256, 256, 0, stream>>>(hs, Xb);
  transpose_f32_bf16<1><<<dim3(NPROJ / 64, QDIM / 256), 256, 0, stream>>>(Wqkv, Wqkvt, QDIM,
                                                                          NPROJ);
  transpose_f32_bf16<0><<<dim3(QDIM / 64, NCAT / 256), 256, 0, stream>>>(Wout, Woutt, NCAT,
                                                                         QDIM);

  // 2a) QKV projection + fused RMSNorm/RoPE (+V transpose) -> Qb/Kb/Vt directly
  gemm_qkv<<<dim3(NQKV / 128, MROWS / 128), 256, 0, stream>>>(Xb, Wqkvt, rcos, rsin, wq, wk,
                                                              Qb, Kb, Vt, QDIM);
  // 2b) MLP projection + fused SwiGLU -> Cat[:, 2048:10240] — ring-4 256² pipeline
  gemm_mlp<<<dim3(NMLP / 256, MROWS / 256), 512, 0, stream>>>(
      Xb, Wqkvt + (size_t)NQKV * QDIM, Cat + QDIM, QDIM);

  // 3) flash attention -> Cat[:, 0:2048]
  attn_fwd<<<S_LEN / 128 * NBH, 256, 0, stream>>>(Qb, Kb, Vt, Cat);

  // 4) output projection + bias (f32 out)
  gemm_bt<<<dim3(QDIM / 128, MROWS / 128), 256, 0, stream>>>(Cat, Woutt, out, bout, QDIM,
                                                             NCAT);
}

// Round 11
// 766.251 us; speedup vs baseline: 1.0310x; 1.0310x over previous
//
#include <hip/hip_runtime.h>

typedef unsigned short u16;
typedef unsigned int u32;
typedef __bf16 bf16x8 __attribute__((ext_vector_type(8)));
typedef float f32x4 __attribute__((ext_vector_type(4)));

#define MFMA16(a, b, c) __builtin_amdgcn_mfma_f32_16x16x32_bf16((a), (b), (c), 0, 0, 0)

// ---- constants ----
#define S_LEN 2048
#define D_HEAD 128
#define NHEADS 16
#define NBH 32          // B*HEADS
#define QDIM 2048
#define NPROJ 22528     // 3*INNER + 2*MLP_HID
#define NQKV 6144       // 3*INNER
#define NMLP 16384      // 2*MLP_HID
#define NCAT 10240      // INNER + MLP_HID
#define MROWS 4096      // B*S

#define BARRIER() __builtin_amdgcn_s_barrier()
#define WAITVM0() asm volatile("s_waitcnt vmcnt(0)" ::: "memory")

__device__ __forceinline__ float bf2f(u16 u) { return __uint_as_float(((u32)u) << 16); }
__device__ __forceinline__ u16 f2bf(float f) {
  u32 u = __float_as_uint(f);
  return (u16)((u + 0x7FFFu + ((u >> 16) & 1u)) >> 16);
}
__device__ __forceinline__ void gld16(const void* g, void* l) {
  __builtin_amdgcn_global_load_lds((__attribute__((address_space(1))) void*)(g),
                                   (__attribute__((address_space(3))) void*)(l), 16, 0, 0);
}

// ---------------- f32 -> bf16 elementwise (vectorized) ----------------
__global__ __launch_bounds__(256) void f32_to_bf16(const float* __restrict__ in,
                                                   u16* __restrict__ out) {
  const u32 i = blockIdx.x * 256 + threadIdx.x;  // one float4 per thread
  const float4 v = ((const float4*)in)[i];
  uint2 o;
  o.x = (u32)f2bf(v.x) | ((u32)f2bf(v.y) << 16);
  o.y = (u32)f2bf(v.z) | ((u32)f2bf(v.w) << 16);
  ((uint2*)out)[i] = o;
}

// -------- merged transpose-convert: both weight matrices in one launch --------
// Part 1 (blocks [0, nblk1)):  Wqkv [QDIM][NPROJ] -> Wqkvt [NPROJ][QDIM], with
//   the m1/m2 16-row interleave remap on rows >= NQKV (for fused SwiGLU).
// Part 2 (blocks [nblk1, ..)): Wout [NCAT][QDIM] -> Woutt [QDIM][NCAT].
// Tile: 256 R-rows x 64 C-cols; LDS [64][260]; store = one 512B row per wave.
__global__ __launch_bounds__(256) void transpose_both(const float* __restrict__ in1,
                                                      u16* __restrict__ out1,
                                                      const float* __restrict__ in2,
                                                      u16* __restrict__ out2, int nblk1) {
  const float* in;
  u16* out;
  int R, C, bx, remap;
  if ((int)blockIdx.x < nblk1) {
    in = in1; out = out1; R = QDIM; C = NPROJ; bx = blockIdx.x; remap = 1;
  } else {
    in = in2; out = out2; R = NCAT; C = QDIM; bx = blockIdx.x - nblk1; remap = 0;
  }
  const int nbc = C / 64;
  const int cb = bx % nbc;
  const int rb = bx / nbc;

  __shared__ u16 tile[64][260];
  const int t = threadIdx.x;
  const int tx = t & 63;   // column (C-dim)
  const int ty = t >> 6;   // 0..3
  const int c0 = cb * 64;
  const int r0 = rb * 256;

#pragma unroll 8
  for (int it = 0; it < 64; ++it) {
    const int rr = it * 4 + ty;
    tile[tx][rr] = f2bf(in[(size_t)(r0 + rr) * C + c0 + tx]);
  }
  __syncthreads();

  const int pos = t & 63;
#pragma unroll 4
  for (int i = 0; i < 16; ++i) {
    const int cc = i * 4 + (t >> 6);
    int orow = c0 + cc;
    if (remap && orow >= NQKV) {
      const int c = orow - NQKV;
      const int f = c & 8191;
      const int sel = c >> 13;
      orow = NQKV + (((f >> 4) << 5) | (sel << 4) | (f & 15));
    }
    const u32 lo = (u32)tile[cc][pos * 4] | ((u32)tile[cc][pos * 4 + 1] << 16);
    const u32 hi = (u32)tile[cc][pos * 4 + 2] | ((u32)tile[cc][pos * 4 + 3] << 16);
    uint2 v;
    v.x = lo;
    v.y = hi;
    *(uint2*)&out[(size_t)orow * R + r0 + pos * 4] = v;
  }
}

// ---------------- 128x128 bf16 GEMM (m97 structure, plain 2-D grid) ----------------
// OUTMODE 1: f32 + bias (GEMM2). OUTMODE 2: fused SwiGLU (MLP; B rows
// interleaved m1/m2 in 16-row groups; out ptr pre-offset to Cat+QDIM).
template <int OUTMODE>
__global__ __launch_bounds__(256, 2) void gemm_bt(const u16* __restrict__ A,
                                                  const u16* __restrict__ Bt,
                                                  void* __restrict__ Cvoid,
                                                  const float* __restrict__ bias, int N, int K) {
  __shared__ u16 As[128 * 64];
  __shared__ u16 Bs[128 * 64];
  const int t = threadIdx.x;
  const int l = t & 63;
  const int w = t >> 6;
  const int lr = l & 15;
  const int lg = l >> 4;
  const int m0 = blockIdx.y * 128;
  const int n0 = blockIdx.x * 128;
  const int wm = (w >> 1) * 64;
  const int wn = (w & 1) * 64;

  f32x4 acc[4][4] = {};
  const int obase = w * 1024 + l * 16;

  for (int k0 = 0; k0 < K; k0 += 64) {
#pragma unroll
    for (int rnd = 0; rnd < 4; ++rnd) {
      const int o = obase + rnd * 4096;
      const int row = o >> 7;
      const int g = (o & 127) >> 4;
      const int gs = g ^ (row & 7);
      gld16(A + (size_t)(m0 + row) * K + k0 + gs * 8, &As[rnd * 2048 + w * 512]);
      gld16(Bt + (size_t)(n0 + row) * K + k0 + gs * 8, &Bs[rnd * 2048 + w * 512]);
    }
    __syncthreads();

    bf16x8 af[4][2], bfr[4][2];
#pragma unroll
    for (int i = 0; i < 4; ++i) {
#pragma unroll
      for (int kc = 0; kc < 2; ++kc) {
        const int ra = wm + i * 16 + lr;
        af[i][kc] = *(const bf16x8*)&As[ra * 64 + (((kc * 4 + lg) ^ (ra & 7)) * 8)];
        const int rb = wn + i * 16 + lr;
        bfr[i][kc] = *(const bf16x8*)&Bs[rb * 64 + (((kc * 4 + lg) ^ (rb & 7)) * 8)];
      }
    }
#pragma unroll
    for (int kc = 0; kc < 2; ++kc)
#pragma unroll
      for (int i = 0; i < 4; ++i)
#pragma unroll
        for (int j = 0; j < 4; ++j)
          acc[i][j] = MFMA16(af[i][kc], bfr[j][kc], acc[i][j]);
    __syncthreads();
  }

  if (OUTMODE == 1) {
    float* C = (float*)Cvoid;
#pragma unroll
    for (int i = 0; i < 4; ++i)
#pragma unroll
      for (int j = 0; j < 4; ++j)
#pragma unroll
        for (int r = 0; r < 4; ++r) {
          const int row = m0 + wm + i * 16 + lg * 4 + r;
          const int col = n0 + wn + j * 16 + lr;
          C[(size_t)row * N + col] = acc[i][j][r] + bias[col];
        }
  } else {
    // fused SwiGLU: j=2jj holds m1, j=2jj+1 holds m2 (same lane, same cols)
    u16* C = (u16*)Cvoid;  // pre-offset to Cat + QDIM
#pragma unroll
    for (int i = 0; i < 4; ++i)
#pragma unroll
      for (int jj = 0; jj < 2; ++jj)
#pragma unroll
        for (int r = 0; r < 4; ++r) {
          const int row = m0 + wm + i * 16 + lg * 4 + r;
          const float a1 = acc[i][2 * jj][r];
          const float a2 = acc[i][2 * jj + 1][r];
          const float fz = a1 / (1.f + __expf(-a1)) * a2;
          const int col = ((n0 + wn) >> 1) + jj * 16 + lr;
          C[(size_t)row * N + col] = f2bf(fz);
        }
  }
}

// ------------- QKV GEMM with fused RMSNorm + RoPE + V-transpose epilogue -------------
// Same m97 K-loop. Each 128-col block = one head of one of Q/K/V.
// Q pre-scaled by 128^-0.5 * log2(e) so attention uses exp2 directly.
// V blocks: LDS-transpose (reusing the 32KB staging LDS, XOR-swizzled) then
// coalesced store straight to Vt[bh][d][s] — no Vb buffer, no transpose kernel.
__global__ __launch_bounds__(256, 2) void gemm_qkv(const u16* __restrict__ A,
                                                   const u16* __restrict__ Bt,
                                                   const float* __restrict__ cosT,
                                                   const float* __restrict__ sinT,
                                                   const float* __restrict__ wq,
                                                   const float* __restrict__ wk,
                                                   u16* __restrict__ Qb, u16* __restrict__ Kb,
                                                   u16* __restrict__ Vt, int K) {
  __shared__ u16 smem[2][128 * 64];  // As | Bs ; reused as 128x128 V-tile
  __shared__ float redbuf[2][128];
  u16* As = smem[0];
  u16* Bs = smem[1];
  const int t = threadIdx.x;
  const int l = t & 63;
  const int w = t >> 6;
  const int lr = l & 15;
  const int lg = l >> 4;
  const int m0 = blockIdx.y * 128;
  const int n0 = blockIdx.x * 128;
  const int wm = (w >> 1) * 64;
  const int wn = (w & 1) * 64;

  f32x4 acc[4][4] = {};
  const int obase = w * 1024 + l * 16;

  for (int k0 = 0; k0 < K; k0 += 64) {
#pragma unroll
    for (int rnd = 0; rnd < 4; ++rnd) {
      const int o = obase + rnd * 4096;
      const int row = o >> 7;
      const int g = (o & 127) >> 4;
      const int gs = g ^ (row & 7);
      gld16(A + (size_t)(m0 + row) * K + k0 + gs * 8, As + rnd * 2048 + w * 512);
      gld16(Bt + (size_t)(n0 + row) * K + k0 + gs * 8, Bs + rnd * 2048 + w * 512);
    }
    __syncthreads();

    bf16x8 af[4][2], bfr[4][2];
#pragma unroll
    for (int i = 0; i < 4; ++i) {
#pragma unroll
      for (int kc = 0; kc < 2; ++kc) {
        const int ra = wm + i * 16 + lr;
        af[i][kc] = *(const bf16x8*)&As[ra * 64 + (((kc * 4 + lg) ^ (ra & 7)) * 8)];
        const int rb = wn + i * 16 + lr;
        bfr[i][kc] = *(const bf16x8*)&Bs[rb * 64 + (((kc * 4 + lg) ^ (rb & 7)) * 8)];
      }
    }
#pragma unroll
    for (int kc = 0; kc < 2; ++kc)
#pragma unroll
      for (int i = 0; i < 4; ++i)
#pragma unroll
        for (int j = 0; j < 4; ++j)
          acc[i][j] = MFMA16(af[i][kc], bfr[j][kc], acc[i][j]);
    __syncthreads();
  }

  const int type = n0 >> 11;  // 0=Q, 1=K, 2=V
  const int h = (n0 >> 7) & 15;
  const int b = m0 >> 11;
  const int s0 = m0 & 2047;
  const int bh = b * 16 + h;

  if (type == 2) {
    u16* vt = smem[0];  // 128x128 u16 = 32 KB
#pragma unroll
    for (int i = 0; i < 4; ++i)
#pragma unroll
      for (int j = 0; j < 4; ++j)
#pragma unroll
        for (int r = 0; r < 4; ++r) {
          const int s_loc = wm + i * 16 + lg * 4 + r;
          const int d = wn + j * 16 + lr;
          vt[d * 128 + (s_loc ^ ((d & 7) << 3))] = f2bf(acc[i][j][r]);
        }
    __syncthreads();
    const int g = t & 15;
#pragma unroll
    for (int i = 0; i < 8; ++i) {
      const int d2 = i * 16 + (t >> 4);
      const bf16x8 v = *(const bf16x8*)&vt[d2 * 128 + ((g ^ (d2 & 7)) * 8)];
      *(bf16x8*)&Vt[((size_t)(bh * 128 + d2)) * S_LEN + s0 + g * 8] = v;
    }
    return;
  }

  u16* dst = (type == 0) ? Qb : Kb;

  float ssum[4][4];
#pragma unroll
  for (int i = 0; i < 4; ++i)
#pragma unroll
    for (int r = 0; r < 4; ++r) {
      float p = acc[i][0][r] * acc[i][0][r] + acc[i][1][r] * acc[i][1][r] +
                acc[i][2][r] * acc[i][2][r] + acc[i][3][r] * acc[i][3][r];
      p += __shfl_xor(p, 1);
      p += __shfl_xor(p, 2);
      p += __shfl_xor(p, 4);
      p += __shfl_xor(p, 8);
      ssum[i][r] = p;
    }
  if (lr == 0) {
#pragma unroll
    for (int i = 0; i < 4; ++i)
#pragma unroll
      for (int r = 0; r < 4; ++r) redbuf[wn >> 6][wm + i * 16 + lg * 4 + r] = ssum[i][r];
  }
  __syncthreads();

  const float* wgt = type ? wk : wq;
  // Q pre-scale: 128^-0.5 * log2(e) (attention uses exp2)
  const float sc = type ? 1.0f : 0.12751744f;
#pragma unroll
  for (int i = 0; i < 4; ++i)
#pragma unroll
    for (int r = 0; r < 4; ++r) {
      const int lrow = wm + i * 16 + lg * 4 + r;
      const float tot = redbuf[0][lrow] + redbuf[1][lrow];
      const float rsq = rsqrtf(tot * (1.0f / 128.0f) + 1e-5f) * sc;
      const int s = (m0 + lrow) & 2047;
      const size_t rbase = ((size_t)bh * S_LEN + s) * 128;
#pragma unroll
      for (int j = 0; j < 4; ++j) {
        const int col = wn + j * 16 + lr;
        const float xn = acc[i][j][r] * rsq * wgt[col];
        const float pr = __shfl_xor(xn, 1);
        const float c = cosT[s * 128 + col];
        const float sn = sinT[s * 128 + col];
        const float val = (col & 1) ? (xn * c + pr * sn) : (xn * c - pr * sn);
        dst[rbase + col] = f2bf(val);
      }
    }
}

// ---------------- flash attention: 4 waves x 32 q-rows, KV tile = 64 ----------------
// No-max softmax via exp2 (log2e baked into Q); per-lane l partials, reduced once
// in epilogue. Double-buffered K/V; setprio on MFMA. XCD-chunked block swizzle.
__global__ __launch_bounds__(256, 2) void attn_fwd(const u16* __restrict__ Qb,
                                                   const u16* __restrict__ Kb,
                                                   const u16* __restrict__ Vt,
                                                   u16* __restrict__ Cat) {
  __shared__ u16 Ks[2][64 * 128];   // [key][d], swz g^=key&7
  __shared__ u16 Vs[2][128 * 64];   // [d][key], swz g^=d&7
  __shared__ u16 Ps[4][32 * 64];    // per-wave P [q][key], swz g^=q&7

  const int t = threadIdx.x;
  const int l = t & 63;
  const int w = t >> 6;
  const int lr = l & 15;
  const int lg = l >> 4;
  const int swz = (blockIdx.x & 7) * 64 + (blockIdx.x >> 3);
  const int qt = swz & 15;
  const int bh = swz >> 4;
  const int b = bh >> 4;
  const int h = bh & 15;
  const int q0 = qt * 128 + w * 32;
  const int obase = w * 1024 + l * 16;

  const size_t kbase = (size_t)bh * S_LEN * 128;
  const size_t vbase = (size_t)bh * 128 * S_LEN;

  bf16x8 qf[2][4];
#pragma unroll
  for (int im = 0; im < 2; ++im)
#pragma unroll
    for (int kc = 0; kc < 4; ++kc)
      qf[im][kc] =
          *(const bf16x8*)&Qb[((size_t)bh * S_LEN + q0 + im * 16 + lr) * 128 + kc * 32 + lg * 8];

  f32x4 oacc[2][8] = {};
  float lrun[2][4] = {};

  u16* P = Ps[w];

  auto stageKV = [&](int buf, int kt2) {
    const int kk0 = kt2 * 64;
#pragma unroll
    for (int rnd = 0; rnd < 4; ++rnd) {
      const int o = obase + rnd * 4096;
      {
        const int key = o >> 8;
        const int g = (o & 255) >> 4;
        const int gs = g ^ (key & 7);
        gld16(Kb + kbase + (size_t)(kk0 + key) * 128 + gs * 8,
              &Ks[buf][rnd * 2048 + w * 512]);
      }
      {
        const int d = o >> 7;
        const int g = (o & 127) >> 4;
        const int gs = g ^ (d & 7);
        gld16(Vt + vbase + (size_t)d * S_LEN + kk0 + gs * 8,
              &Vs[buf][rnd * 2048 + w * 512]);
      }
    }
  };

  stageKV(0, 0);
  WAITVM0();
  BARRIER();

  int cur = 0;
  for (int kt = 0; kt < 32; ++kt) {
    if (kt + 1 < 32) stageKV(cur ^ 1, kt + 1);

    const u16* Kc = &Ks[cur][0];
    const u16* Vc = &Vs[cur][0];

    f32x4 sf[2][4] = {};
    __builtin_amdgcn_s_setprio(1);
#pragma unroll
    for (int j = 0; j < 4; ++j) {
      const int kr = j * 16 + lr;
      bf16x8 kf[4];
#pragma unroll
      for (int kc = 0; kc < 4; ++kc)
        kf[kc] = *(const bf16x8*)&Kc[kr * 128 + (((kc * 4 + lg) ^ (kr & 7)) * 8)];
#pragma unroll
      for (int kc = 0; kc < 4; ++kc)
#pragma unroll
        for (int im = 0; im < 2; ++im)
          sf[im][j] = MFMA16(qf[im][kc], kf[kc], sf[im][j]);
    }
    __builtin_amdgcn_s_setprio(0);

#pragma unroll
    for (int im = 0; im < 2; ++im)
#pragma unroll
      for (int r = 0; r < 4; ++r) {
        float psum = 0.f;
#pragma unroll
        for (int j = 0; j < 4; ++j) {
          const float pv = exp2f(sf[im][j][r]);
          sf[im][j][r] = pv;
          psum += pv;
        }
        lrun[im][r] += psum;
      }

#pragma unroll
    for (int im = 0; im < 2; ++im)
#pragma unroll
      for (int j = 0; j < 4; ++j)
#pragma unroll
        for (int r = 0; r < 4; ++r) {
          const int q = im * 16 + lg * 4 + r;
          const int key = j * 16 + lr;
          const int g = key >> 3;
          P[q * 64 + ((g ^ (q & 7)) * 8) + (key & 7)] = f2bf(sf[im][j][r]);
        }

    __builtin_amdgcn_s_setprio(1);
#pragma unroll
    for (int kc = 0; kc < 2; ++kc) {
      bf16x8 pa[2];
#pragma unroll
      for (int im = 0; im < 2; ++im) {
        const int q = im * 16 + lr;
        pa[im] = *(const bf16x8*)&P[q * 64 + (((kc * 4 + lg) ^ (q & 7)) * 8)];
      }
#pragma unroll
      for (int df = 0; df < 8; ++df) {
        const int d = df * 16 + lr;
        const bf16x8 vb = *(const bf16x8*)&Vc[d * 64 + (((kc * 4 + lg) ^ (d & 7)) * 8)];
#pragma unroll
        for (int im = 0; im < 2; ++im) oacc[im][df] = MFMA16(pa[im], vb, oacc[im][df]);
      }
    }
    __builtin_amdgcn_s_setprio(0);

    WAITVM0();
    BARRIER();
    cur ^= 1;
  }

#pragma unroll
  for (int im = 0; im < 2; ++im)
#pragma unroll
    for (int r = 0; r < 4; ++r) {
      float tot = lrun[im][r];
      tot += __shfl_xor(tot, 1);
      tot += __shfl_xor(tot, 2);
      tot += __shfl_xor(tot, 4);
      tot += __shfl_xor(tot, 8);
      const float inv = 1.0f / tot;
      const int row = b * S_LEN + q0 + im * 16 + lg * 4 + r;
#pragma unroll
      for (int df = 0; df < 8; ++df) {
        const int col = h * 128 + df * 16 + lr;
        Cat[(size_t)row * NCAT + col] = f2bf(oacc[im][df][r] * inv);
      }
    }
}

// ---------------- launch ----------------
extern "C" void kernel_launch(void* const* d_in, const int* in_sizes, int n_in, void* d_out,
                              int out_size, void* d_ws, size_t ws_size, hipStream_t stream) {
  (void)in_sizes; (void)n_in; (void)out_size; (void)ws_size;
  const float* hs = (const float*)d_in[0];
  const float* rcos = (const float*)d_in[1];
  const float* rsin = (const float*)d_in[2];
  const float* Wqkv = (const float*)d_in[3];
  const float* wq = (const float*)d_in[4];
  const float* wk = (const float*)d_in[5];
  const float* Wout = (const float*)d_in[6];
  const float* bout = (const float*)d_in[7];
  float* out = (float*)d_out;

  char* ws = (char*)d_ws;
  size_t off = 0;
  auto nxt = [&](size_t bytes) {
    char* p = ws + off;
    off += (bytes + 255) & ~(size_t)255;
    return p;
  };
  u16* Xb = (u16*)nxt((size_t)MROWS * QDIM * 2);          // 16.8 MB
  u16* Wqkvt = (u16*)nxt((size_t)NPROJ * QDIM * 2);       // 92.3 MB
  u16* Woutt = (u16*)nxt((size_t)QDIM * NCAT * 2);        // 41.9 MB
  u16* Qb = (u16*)nxt((size_t)NBH * S_LEN * D_HEAD * 2);  // 16.8 MB
  u16* Kb = (u16*)nxt((size_t)NBH * S_LEN * D_HEAD * 2);
  u16* Vt = (u16*)nxt((size_t)NBH * S_LEN * D_HEAD * 2);
  u16* Cat = (u16*)nxt((size_t)MROWS * NCAT * 2);         // 83.9 MB

  // 1) convert X; transpose both weight matrices in one launch
  f32_to_bf16<<<(MROWS * QDIM / 4) / 256, 256, 0, stream>>>(hs, Xb);
  const int nblk1 = (NPROJ / 64) * (QDIM / 256);   // 352*8 = 2816
  const int nblk2 = (QDIM / 64) * (NCAT / 256);    // 32*40 = 1280
  transpose_both<<<nblk1 + nblk2, 256, 0, stream>>>(Wqkv, Wqkvt, Wout, Woutt, nblk1);

  // 2a) QKV projection + fused RMSNorm/RoPE (+V transpose) -> Qb/Kb/Vt directly
  gemm_qkv<<<dim3(NQKV / 128, MROWS / 128), 256, 0, stream>>>(Xb, Wqkvt, rcos, rsin, wq, wk,
                                                              Qb, Kb, Vt, QDIM);
  // 2b) MLP projection + fused SwiGLU -> Cat[:, 2048:10240]
  gemm_bt<2><<<dim3(NMLP / 128, MROWS / 128), 256, 0, stream>>>(
      Xb, Wqkvt + (size_t)NQKV * QDIM, Cat + QDIM, nullptr, NCAT, QDIM);

  // 3) flash attention -> Cat[:, 0:2048]
  attn_fwd<<<S_LEN / 128 * NBH, 256, 0, stream>>>(Qb, Kb, Vt, Cat);

  // 4) output projection + bias (f32 out)
  gemm_bt<1><<<dim3(QDIM / 128, MROWS / 128), 256, 0, stream>>>(Cat, Woutt, out, bout, QDIM,
                                                                NCAT);
}